// Round 6
// baseline (540.984 us; speedup 1.0000x reference)
//
#include <hip/hip_runtime.h>
#include <math.h>

#define C_CH 512
#define T_LEN 4096
#define NTT 32            // t tiles of 128

typedef unsigned short bf16_t;
typedef short bf16x8 __attribute__((ext_vector_type(8)));
typedef float f32x4 __attribute__((ext_vector_type(4)));

__device__ inline bf16_t f2bf(float x) {
  unsigned u = __float_as_uint(x);
  return (bf16_t)((u + 0x7FFF + ((u >> 16) & 1)) >> 16);
}
__device__ inline float bf2f(bf16_t h) { return __uint_as_float(((unsigned)h) << 16); }

// ---- ws float offsets ----
#define OFF_FILT 0
#define OFF_S1   64
#define OFF_S2   576
#define OFF_S3   2624
#define OFF_WFP  4096                  // 8 * 512*512 f32 partials
#define OFF_WP1  2101248               // 7*512*512 bf16
#define OFF_WPF  3018752               // 512*512 bf16
#define OFF_H1   3149824               // 4*512*4096 bf16 (tiled layout)
#define OFF_H2   7344128
#define OFF_H3   11538432

__device__ double i0d(double x) {
  double t = 0.5 * x, t2 = t * t;
  double term = 1.0, sum = 1.0;
  for (int k = 1; k < 60; ++k) {
    term *= t2 / ((double)k * (double)k);
    sum += term;
    if (term < 1e-17 * sum) break;
  }
  return sum;
}

__global__ __launch_bounds__(256) void init_consts(
    const float* __restrict__ v1, const float* __restrict__ g1,
    const float* __restrict__ v2, const float* __restrict__ g2,
    const float* __restrict__ v3, const float* __restrict__ g3,
    float* __restrict__ ws)
{
  int blk = blockIdx.x;
  if (blk == 3072) {
    if (threadIdx.x == 0) {
      double beta = 0.1102 * (2.285 * 5.0 * M_PI * 1.2 + 7.95 - 8.7);
      double ib = i0d(beta);
      double f[12]; double s = 0.0;
      for (int n = 0; n < 12; ++n) {
        double r = ((double)n - 5.5) / 5.5;
        double w = i0d(beta * sqrt(fmax(0.0, 1.0 - r * r))) / ib;
        double tt = ((double)n - 5.5) * 0.5;
        double sc = sin(M_PI * tt) / (M_PI * tt);
        f[n] = 0.5 * w * sc;
        s += f[n];
      }
      for (int n = 0; n < 12; ++n) ws[OFF_FILT + n] = (float)(f[n] / s);
    }
    return;
  }
  const float* v; const float* g; int len; float* out;
  if (blk < 512)       { v = v1 + (size_t)blk * 3584;        g = g1 + blk;        len = 3584; out = ws + OFF_S1 + blk; }
  else if (blk < 2560) { int m = blk - 512;  v = v2 + (size_t)m * 512;  g = g2 + m; len = 512;  out = ws + OFF_S2 + m; }
  else                 { int m = blk - 2560; v = v3 + (size_t)m * 2048; g = g3 + m; len = 2048; out = ws + OFF_S3 + m; }
  float s = 0.f;
  for (int i = threadIdx.x; i < len; i += 256) { float x = v[i]; s = fmaf(x, x, s); }
  #pragma unroll
  for (int off = 32; off > 0; off >>= 1) s += __shfl_down(s, off);
  __shared__ float red[4];
  int lane = threadIdx.x & 63, w = threadIdx.x >> 6;
  if (lane == 0) red[w] = s;
  __syncthreads();
  if (threadIdx.x == 0) {
    float tot = red[0] + red[1] + red[2] + red[3];
    *out = g[0] / sqrtf(tot);
  }
}

// split-K weight fusion
__global__ __launch_bounds__(256) void fuse_w(
    const float* __restrict__ v2, const float* __restrict__ v3,
    float* __restrict__ ws)
{
  const float* s2 = ws + OFF_S2;
  float* wfp = ws + OFF_WFP;
  __shared__ float a[32][68];
  __shared__ float bsh[32][68];
  int i0 = blockIdx.x * 64, o0 = blockIdx.y * 64;
  int mbase = blockIdx.z * 256;
  int tid = threadIdx.x;
  int ii = tid & 15, io = tid >> 4;
  float acc[4][4] = {};
  for (int m0 = mbase; m0 < mbase + 256; m0 += 32) {
    for (int idx = tid; idx < 2048; idx += 256) {
      int o_l = idx >> 5, mm = idx & 31;
      a[mm][o_l] = v3[(size_t)(o0 + o_l) * 2048 + m0 + mm];
    }
    for (int idx = tid; idx < 2048; idx += 256) {
      int mm = idx >> 6, i_l = idx & 63;
      bsh[mm][i_l] = v2[(size_t)(m0 + mm) * 512 + i0 + i_l] * s2[m0 + mm];
    }
    __syncthreads();
    #pragma unroll 8
    for (int mm = 0; mm < 32; ++mm) {
      float4 av = *(const float4*)&a[mm][io * 4];
      float4 bv = *(const float4*)&bsh[mm][ii * 4];
      float ar[4] = {av.x, av.y, av.z, av.w};
      float br[4] = {bv.x, bv.y, bv.z, bv.w};
      #pragma unroll
      for (int p = 0; p < 4; ++p)
        #pragma unroll
        for (int q = 0; q < 4; ++q)
          acc[p][q] = fmaf(ar[p], br[q], acc[p][q]);
    }
    __syncthreads();
  }
  float* wout = wfp + (size_t)blockIdx.z * 512 * 512;
  #pragma unroll
  for (int p = 0; p < 4; ++p) {
    int o = o0 + io * 4 + p;
    float4 r;
    r.x = acc[p][0]; r.y = acc[p][1]; r.z = acc[p][2]; r.w = acc[p][3];
    *(float4*)&wout[(size_t)o * 512 + i0 + ii * 4] = r;
  }
}

__global__ __launch_bounds__(256) void wfpack(
    const float* __restrict__ wfp, const float* __restrict__ s3,
    bf16_t* __restrict__ wpf)
{
  int idx = blockIdx.x * 256 + threadIdx.x;
  int o = idx >> 9;
  float s = 0.f;
  #pragma unroll
  for (int kc = 0; kc < 8; ++kc) s += wfp[(size_t)kc * 262144 + idx];
  wpf[idx] = f2bf(s * s3[o]);
}

__global__ __launch_bounds__(256) void wprep1(
    const float* __restrict__ v1, const float* __restrict__ s1w,
    bf16_t* __restrict__ wp)
{
  int idx = blockIdx.x * 256 + threadIdx.x;
  int i = idx & 511;
  int o = (idx >> 9) & 511;
  int tap = idx >> 18;
  wp[idx] = f2bf(v1[((size_t)o * 512 + i) * 7 + tap] * s1w[o]);
}

// fused act1d on channel-last tiles.
// Block: (tt, 64-ch tile, b), 256 threads = 16 t-strips x 16 ch-groups (x4 iters).
// Output layout: dst[b][tt][tl 0..127][ch 0..511] bf16.
// SRC=0: src = x (f32, NCH). SRC=1: src = tiled bf16 H.
template <int SRC>
__global__ __launch_bounds__(256) void act_tiled(
    const void* __restrict__ srcp, bf16_t* __restrict__ dst,
    const float* __restrict__ alpha, const float* __restrict__ beta,
    const float* __restrict__ filt_g)
{
  __shared__ bf16_t xs[144][66];              // xs[j][cc] = src[c0+cc][clamp(t0-6+j)]
  __shared__ __align__(16) bf16_t hsh[128 * 64];
  __shared__ float F[12];
  const int tt = blockIdx.x;
  const int c0 = blockIdx.y * 64;
  const int b  = blockIdx.z;
  const int t0 = tt * 128;
  const int tid = threadIdx.x;
  if (tid < 12) F[tid] = filt_g[tid];

  if (SRC == 0) {
    const float* xg = (const float*)srcp + ((size_t)b * C_CH + c0) * T_LEN;
    for (int u = tid; u < 64 * 18; u += 256) {
      int cc = u / 18, og = u - cc * 18;
      const float* row = xg + (size_t)cc * T_LEN;
      #pragma unroll
      for (int i = 0; i < 8; ++i) {
        int gt = t0 - 6 + og * 8 + i;
        gt = min(max(gt, 0), T_LEN - 1);
        xs[og * 8 + i][cc] = f2bf(row[gt]);
      }
    }
  } else {
    const bf16_t* hg = (const bf16_t*)srcp + (size_t)b * NTT * 128 * 512;
    for (int u = tid; u < 144 * 8; u += 256) {
      int j = u >> 3, oct = u & 7;
      int gt = min(max(t0 - 6 + j, 0), T_LEN - 1);
      bf16x8 v = *(const bf16x8*)&hg[((size_t)(gt >> 7) * 128 + (gt & 127)) * 512 + c0 + oct * 8];
      #pragma unroll
      for (int i = 0; i < 8; ++i) xs[j][oct * 8 + i] = (bf16_t)v[i];
    }
  }
  __syncthreads();

  const int s = tid & 15;           // t-strip (8 outputs)
  const int cgl = tid >> 4;         // 0..15
  #pragma unroll
  for (int it = 0; it < 4; ++it) {
    int cc = cgl + it * 16;
    float ea = __expf(alpha[c0 + cc]);
    float ib = 1.0f / (__expf(beta[c0 + cc]) + 1e-9f);
    int gts = t0 + s * 8;
    float yv[26];
    #pragma unroll
    for (int m = 0; m < 26; ++m) {
      int n = 2 * gts - 5 + m;
      n = min(max(n, 0), 2 * T_LEN - 1);
      int tp = n >> 1;
      int jb = tp - t0 + 6;          // xs row of x[tp]
      float sa = 0.f;
      if (n & 1) {
        #pragma unroll
        for (int u = 0; u < 6; ++u) sa = fmaf(bf2f(xs[jb - 2 + u][cc]), F[10 - 2 * u], sa);
      } else {
        #pragma unroll
        for (int u = 0; u < 6; ++u) sa = fmaf(bf2f(xs[jb - 3 + u][cc]), F[11 - 2 * u], sa);
      }
      float y = 2.f * sa;
      float sn = __sinf(y * ea);
      yv[m] = fmaf(ib * sn, sn, y);
    }
    #pragma unroll
    for (int j = 0; j < 8; ++j) {
      float h = 0.f;
      #pragma unroll
      for (int k = 0; k < 12; ++k) h = fmaf(F[k], yv[2 * j + k], h);
      int tl = s * 8 + j;
      int byteoff = tl * 128 + ((cc * 2) ^ ((s & 7) << 4));
      *(bf16_t*)((char*)hsh + byteoff) = f2bf(h);
    }
  }
  __syncthreads();
  bf16_t* drow = dst + ((size_t)b * NTT + tt) * 128 * 512;
  for (int u = tid; u < 128 * 8; u += 256) {
    int tl = u >> 3, oct = u & 7;
    int byteoff = tl * 128 + ((oct * 16) ^ (((tl >> 3) & 7) << 4));
    bf16x8 v = *(const bf16x8*)((const char*)hsh + byteoff);
    *(bf16x8*)&drow[(size_t)tl * 512 + c0 + oct * 8] = v;
  }
}

// conv K=7, 512->512, zero-pad-3, MFMA 16x16x32 bf16, channel-last tiled I/O.
__global__ __launch_bounds__(256, 2) void conv7_mfma(
    const bf16_t* __restrict__ src, const bf16_t* __restrict__ wp,
    bf16_t* __restrict__ dst)
{
  __shared__ __align__(16) bf16_t Xs[144 * 64];
  const int tt = blockIdx.x;
  const int t0 = tt * 128;
  const int o0 = blockIdx.y * 128;
  const int b  = blockIdx.z;
  const int tid = threadIdx.x;
  const int wave = tid >> 6;
  const int wo = wave >> 1, wt = wave & 1;
  const int lane = tid & 63;
  const int l15 = lane & 15, lhi = lane >> 4;
  f32x4 acc[4][4];
  #pragma unroll
  for (int m = 0; m < 4; ++m)
    #pragma unroll
    for (int n = 0; n < 4; ++n)
      acc[m][n] = (f32x4){0.f, 0.f, 0.f, 0.f};

  const bf16_t* hg = src + (size_t)b * NTT * 128 * 512;
  const int obase = o0 + wo * 64;
  const int trow0 = wt * 64;

  for (int cb = 0; cb < 512; cb += 64) {
    __syncthreads();
    // stage rows [t0-8, t0+136) x 64ch: b128 both sides, XOR swizzle
    for (int u = tid; u < 144 * 8; u += 256) {
      int rl = u >> 3, oct = u & 7;
      int gt = t0 - 8 + rl;
      bf16x8 v = (bf16x8)(short)0;
      if ((unsigned)gt < (unsigned)T_LEN)
        v = *(const bf16x8*)&hg[((size_t)(gt >> 7) * 128 + (gt & 127)) * 512 + cb + oct * 8];
      int byteoff = rl * 128 + ((oct * 16) ^ ((rl & 7) << 4));
      *(bf16x8*)((char*)Xs + byteoff) = v;
    }
    __syncthreads();
    #pragma unroll
    for (int tap = 0; tap < 7; ++tap) {
      #pragma unroll
      for (int ks = 0; ks < 2; ++ks) {
        const int chcol = ks * 32 + lhi * 8;
        bf16x8 a[4];
        #pragma unroll
        for (int m = 0; m < 4; ++m) {
          int o = obase + m * 16 + l15;
          a[m] = *(const bf16x8*)(wp + ((size_t)(tap * 512 + o) * 512) + cb + chcol);
        }
        bf16x8 bfr[4];
        #pragma unroll
        for (int n = 0; n < 4; ++n) {
          int row = trow0 + n * 16 + l15 + tap + 5;
          int byteoff = row * 128 + ((chcol * 2) ^ ((row & 7) << 4));
          bfr[n] = *(const bf16x8*)((const char*)Xs + byteoff);
        }
        #pragma unroll
        for (int m = 0; m < 4; ++m)
          #pragma unroll
          for (int n = 0; n < 4; ++n)
            acc[m][n] = __builtin_amdgcn_mfma_f32_16x16x32_bf16(a[m], bfr[n], acc[m][n], 0, 0, 0);
      }
    }
  }
  // transposed tile store: H2[b][tt][tl][o], 4 consecutive o per lane (b64)
  bf16_t* drow = dst + ((size_t)b * NTT + tt) * 128 * 512;
  #pragma unroll
  for (int m = 0; m < 4; ++m)
    #pragma unroll
    for (int n = 0; n < 4; ++n) {
      int tl = wt * 64 + n * 16 + l15;
      int o = obase + m * 16 + lhi * 4;
      unsigned lo = (unsigned)f2bf(acc[m][n][0]) | ((unsigned)f2bf(acc[m][n][1]) << 16);
      unsigned hi = (unsigned)f2bf(acc[m][n][2]) | ((unsigned)f2bf(acc[m][n][3]) << 16);
      uint2 pv; pv.x = lo; pv.y = hi;
      *(uint2*)&drow[(size_t)tl * 512 + o] = pv;
    }
}

// out = x + wf @ h (1x1), tiled input, NCH f32 residual output
__global__ __launch_bounds__(256, 2) void gemm_mfma(
    const bf16_t* __restrict__ src, const bf16_t* __restrict__ wp,
    const float* __restrict__ x, float* __restrict__ out)
{
  __shared__ __align__(16) bf16_t Xs[128 * 64];
  const int tt = blockIdx.x;
  const int t0 = tt * 128;
  const int o0 = blockIdx.y * 128;
  const int b  = blockIdx.z;
  const int tid = threadIdx.x;
  const int wave = tid >> 6;
  const int wo = wave >> 1, wt = wave & 1;
  const int lane = tid & 63;
  const int l15 = lane & 15, lhi = lane >> 4;
  f32x4 acc[4][4];
  #pragma unroll
  for (int m = 0; m < 4; ++m)
    #pragma unroll
    for (int n = 0; n < 4; ++n)
      acc[m][n] = (f32x4){0.f, 0.f, 0.f, 0.f};

  const bf16_t* hg = src + (size_t)b * NTT * 128 * 512;
  const int obase = o0 + wo * 64;
  const int trow0 = wt * 64;

  for (int cb = 0; cb < 512; cb += 64) {
    __syncthreads();
    for (int u = tid; u < 128 * 8; u += 256) {
      int rl = u >> 3, oct = u & 7;
      bf16x8 v = *(const bf16x8*)&hg[((size_t)tt * 128 + rl) * 512 + cb + oct * 8];
      int byteoff = rl * 128 + ((oct * 16) ^ ((rl & 7) << 4));
      *(bf16x8*)((char*)Xs + byteoff) = v;
    }
    __syncthreads();
    #pragma unroll
    for (int ks = 0; ks < 2; ++ks) {
      const int chcol = ks * 32 + lhi * 8;
      bf16x8 a[4];
      #pragma unroll
      for (int m = 0; m < 4; ++m) {
        int o = obase + m * 16 + l15;
        a[m] = *(const bf16x8*)(wp + (size_t)o * 512 + cb + chcol);
      }
      bf16x8 bfr[4];
      #pragma unroll
      for (int n = 0; n < 4; ++n) {
        int row = trow0 + n * 16 + l15;
        int byteoff = row * 128 + ((chcol * 2) ^ ((row & 7) << 4));
        bfr[n] = *(const bf16x8*)((const char*)Xs + byteoff);
      }
      #pragma unroll
      for (int m = 0; m < 4; ++m)
        #pragma unroll
        for (int n = 0; n < 4; ++n)
          acc[m][n] = __builtin_amdgcn_mfma_f32_16x16x32_bf16(a[m], bfr[n], acc[m][n], 0, 0, 0);
    }
  }
  #pragma unroll
  for (int m = 0; m < 4; ++m)
    #pragma unroll
    for (int n = 0; n < 4; ++n) {
      int t = t0 + wt * 64 + n * 16 + l15;
      #pragma unroll
      for (int r = 0; r < 4; ++r) {
        int o = obase + m * 16 + lhi * 4 + r;
        size_t off = ((size_t)b * C_CH + o) * T_LEN + t;
        out[off] = x[off] + acc[m][n][r];
      }
    }
}

extern "C" void kernel_launch(void* const* d_in, const int* in_sizes, int n_in,
                              void* d_out, int out_size, void* d_ws, size_t ws_size,
                              hipStream_t stream) {
  const float* x  = (const float*)d_in[0];
  const float* a1 = (const float*)d_in[1];
  const float* b1 = (const float*)d_in[2];
  const float* v1 = (const float*)d_in[3];
  const float* g1 = (const float*)d_in[4];
  const float* a2 = (const float*)d_in[5];
  const float* b2 = (const float*)d_in[6];
  const float* v2 = (const float*)d_in[7];
  const float* g2 = (const float*)d_in[8];
  const float* v3 = (const float*)d_in[9];
  const float* g3 = (const float*)d_in[10];
  float* out = (float*)d_out;
  float* ws  = (float*)d_ws;
  bf16_t* wp1 = (bf16_t*)(ws + OFF_WP1);
  bf16_t* wpf = (bf16_t*)(ws + OFF_WPF);
  bf16_t* h1  = (bf16_t*)(ws + OFF_H1);
  bf16_t* h2  = (bf16_t*)(ws + OFF_H2);
  bf16_t* h3  = (bf16_t*)(ws + OFF_H3);

  init_consts<<<3073, 256, 0, stream>>>(v1, g1, v2, g2, v3, g3, ws);
  fuse_w<<<dim3(8, 8, 8), 256, 0, stream>>>(v2, v3, ws);
  wfpack<<<1024, 256, 0, stream>>>(ws + OFF_WFP, ws + OFF_S3, wpf);
  wprep1<<<7168, 256, 0, stream>>>(v1, ws + OFF_S1, wp1);
  act_tiled<0><<<dim3(NTT, 8, 4), 256, 0, stream>>>(x, h1, a1, b1, ws + OFF_FILT);
  conv7_mfma<<<dim3(NTT, 4, 4), 256, 0, stream>>>(h1, wp1, h2);
  act_tiled<1><<<dim3(NTT, 8, 4), 256, 0, stream>>>(h2, h3, a2, b2, ws + OFF_FILT);
  gemm_mfma<<<dim3(NTT, 4, 4), 256, 0, stream>>>(h3, wpf, x, out);
}